// Round 12
// baseline (72.900 us; speedup 1.0000x reference)
//
#include <hip/hip_runtime.h>
#include <math.h>
#include <stdint.h>

#define NTRAIN 16384
#define DIM 64
#define ODIM 8
#define BATCH 8192
#define LOG2E 1.4426950408889634f

typedef float f32x16 __attribute__((ext_vector_type(16)));
typedef short short8 __attribute__((ext_vector_type(8)));
typedef _Float16 f16x8 __attribute__((ext_vector_type(8)));
typedef unsigned short u16;

// float -> bf16 bits, RNE
static __device__ __forceinline__ u16 f2bf(float f) {
  unsigned u = __builtin_bit_cast(unsigned, f);
  u += 0x7FFFu + ((u >> 16) & 1u);
  return (u16)(u >> 16);
}
// float -> fp16 bits, RNE
static __device__ __forceinline__ u16 f2h(float f) {
  return __builtin_bit_cast(u16, (_Float16)f);
}
static __device__ __forceinline__ float h2f(u16 h) {
  return (float)__builtin_bit_cast(_Float16, h);
}

static __device__ __forceinline__ f32x16 mfma_bf(short8 a, short8 b, f32x16 c) {
  return __builtin_amdgcn_mfma_f32_32x32x16_bf16(a, b, c, 0, 0, 0);
}
static __device__ __forceinline__ f32x16 mfma_h(f16x8 a, f16x8 b, f32x16 c) {
  return __builtin_amdgcn_mfma_f32_32x32x16_f16(a, b, c, 0, 0, 0);
}
static __device__ __forceinline__ unsigned pkbf(float a, float b) {
  unsigned d;
  asm("v_cvt_pk_bf16_f32 %0, %1, %2" : "=v"(d) : "v"(a), "v"(b));
  return d;
}
// 2^(-x)
static __device__ __forceinline__ float ex2n(float x) {
  float r;
  asm("v_exp_f32 %0, -%1" : "=v"(r) : "v"(x));
  return r;
}
static __device__ __forceinline__ void plswap(unsigned& a, unsigned& b) {
  asm("v_permlane32_swap_b32 %0, %1" : "+v"(a), "+v"(b));
}

// ---------------------------------------------------------------------------
// k_frag: per 32-n tile, 5 fp16 A-fragments (32x32x16 f16):
//   f=0..3 : 2*gamma_n^2 * x[n][k], k = f*16 + (lane>>5)*8 + j
//   f=4    : norm kstep (lanes hi==0): [gx2_h, gx2_l, g2_h, g2_h, g2_l, 0..]
// plus bf16 V = [1 | y | 0pad] B-fragments.
// ---------------------------------------------------------------------------
__global__ __launch_bounds__(256) void k_frag(
    const float* __restrict__ xt, const float* __restrict__ yt,
    const float* __restrict__ beta,
    u16* __restrict__ xf, u16* __restrict__ yv) {
  int tid = blockIdx.x * 256 + threadIdx.x;

  if (tid < (NTRAIN / 32) * 5 * 64) {
    int fg = tid >> 6, lane = tid & 63;
    int tile = fg / 5, f = fg % 5;
    int lr = lane & 31, hi = lane >> 5;
    uint4 u = {0, 0, 0, 0};
    if (f == 4) {
      if (hi == 0) {
        int n = tile * 32 + lr;
        float g = beta[n] * LOG2E;
        float g2v = g * g;
        const float4* r4 = (const float4*)(xt + (size_t)n * DIM);
        float s0 = 0.f, s1 = 0.f, s2 = 0.f, s3 = 0.f;
#pragma unroll
        for (int q = 0; q < DIM / 4; ++q) {
          float4 v = r4[q];
          s0 = fmaf(v.x, v.x, s0); s1 = fmaf(v.y, v.y, s1);
          s2 = fmaf(v.z, v.z, s2); s3 = fmaf(v.w, v.w, s3);
        }
        float gx2v = g2v * ((s0 + s1) + (s2 + s3));
        u16 xh = f2h(gx2v);
        u16 xl = f2h(gx2v - h2f(xh));
        u16 gh = f2h(g2v);
        u16 gl = f2h(g2v - h2f(gh));
        u.x = (unsigned)xh | ((unsigned)xl << 16);
        u.y = (unsigned)gh | ((unsigned)gh << 16);
        u.z = (unsigned)gl;
      }
    } else {
      int n = tile * 32 + lr;
      float g = beta[n] * LOG2E;
      float s2g = 2.0f * g * g;
      const float* src = xt + (size_t)n * DIM + f * 16 + hi * 8;
      unsigned e[8];
#pragma unroll
      for (int j = 0; j < 8; ++j) e[j] = f2h(s2g * src[j]);
      u.x = e[0] | (e[1] << 16); u.y = e[2] | (e[3] << 16);
      u.z = e[4] | (e[5] << 16); u.w = e[6] | (e[7] << 16);
    }
    ((uint4*)xf)[(size_t)fg * 64 + lane] = u;
    return;
  }
  tid -= (NTRAIN / 32) * 5 * 64;

  if (tid < (NTRAIN / 16) * 64) {  // V fragments (bf16)
    int frag = tid >> 6, lane = tid & 63;
    int col = lane & 31, hi = lane >> 5;
    int n = frag * 16 + hi * 8;
    unsigned e[8];
#pragma unroll
    for (int j = 0; j < 8; ++j) {
      float v = (col == 0) ? 1.0f : ((col < 9) ? yt[(size_t)(n + j) * ODIM + (col - 1)] : 0.0f);
      e[j] = f2bf(v);
    }
    uint4 u;
    u.x = e[0] | (e[1] << 16); u.y = e[2] | (e[3] << 16);
    u.z = e[4] | (e[5] << 16); u.w = e[6] | (e[7] << 16);
    ((uint4*)yv)[(size_t)frag * 64 + lane] = u;
  }
}

// ---------------------------------------------------------------------------
// Pass 1: fp16 S-GEMM + bf16 PV, barrier-free. TWO slabs per iteration with
// interleaved MFMA chains (sA0/sA1) and two independent tails; X registers
// reloaded for slab s+2/s+3 right after their MFMAs consume them (tails cover
// the L2 latency). XCD c-locality swizzle for L2 reuse.
// ---------------------------------------------------------------------------
#define LOAD5(X_, nbv)                                                        \
  {                                                                           \
    const size_t fb_ = (size_t)((nbv) >> 5) * 5;                              \
    _Pragma("unroll")                                                         \
    for (int f = 0; f < 5; ++f) X_[f] = xf4[(fb_ + f) * 64 + lane];           \
  }

#define TAILPV(sA_, V0_, V1_)                                                 \
  {                                                                           \
    unsigned U[8];                                                            \
    _Pragma("unroll")                                                         \
    for (int p = 0; p < 8; ++p) {                                             \
      float d0 = __builtin_amdgcn_sqrtf(fabsf(sA_[2 * p]));                   \
      float d1 = __builtin_amdgcn_sqrtf(fabsf(sA_[2 * p + 1]));               \
      U[p] = pkbf(ex2n(d0), ex2n(d1));                                        \
    }                                                                         \
    plswap(U[0], U[2]); plswap(U[1], U[3]);                                   \
    plswap(U[4], U[6]); plswap(U[5], U[7]);                                   \
    uint4 a1 = {U[0], U[1], U[2], U[3]};                                      \
    uint4 a2 = {U[4], U[5], U[6], U[7]};                                      \
    pv = mfma_bf(__builtin_bit_cast(short8, a1), V0_, pv);                    \
    pv = mfma_bf(__builtin_bit_cast(short8, a2), V1_, pv);                    \
  }

__global__ __launch_bounds__(256, 3) void grnn_pass1(
    const u16* __restrict__ xf, const u16* __restrict__ yv,
    const float* __restrict__ batches,
    float* __restrict__ partial, int chunk_n, int nc) {
  const int lane = threadIdx.x & 63;
  const int lr = lane & 31, hi = lane >> 5;

  // XCD c-locality swizzle (bijective for nc==32).
  int mt, c;
  if (nc == 32) {
    const int bid = blockIdx.x;
    const int xcd = bid & 7;
    const int q = bid >> 3;          // 0..255
    c = xcd + 8 * (q & 3);           // 4 c-slices per XCD
    mt = q >> 2;                     // 0..63
  } else {
    mt = blockIdx.x % (BATCH / 128);
    c = blockIdx.x / (BATCH / 128);
  }
  const int mrow0 = mt * 128 + (threadIdx.x >> 6) * 32;
  const int n0 = c * chunk_n;
  const int nslab = chunk_n / 32;    // even for all nc in {1..32}

  // Batch fragments (B-operand), fp16: 4 ksteps; b2 in-register (plswap).
  f16x8 AH[4], AN;
  const int mrow = mrow0 + lr;
  float ssum = 0.f;
#pragma unroll
  for (int ks = 0; ks < 4; ++ks) {
    const float* src = batches + (size_t)mrow * DIM + ks * 16 + hi * 8;
    float4 v0 = *(const float4*)src;
    float4 v1 = *(const float4*)(src + 4);
    AH[ks][0] = (_Float16)v0.x; AH[ks][1] = (_Float16)v0.y;
    AH[ks][2] = (_Float16)v0.z; AH[ks][3] = (_Float16)v0.w;
    AH[ks][4] = (_Float16)v1.x; AH[ks][5] = (_Float16)v1.y;
    AH[ks][6] = (_Float16)v1.z; AH[ks][7] = (_Float16)v1.w;
    ssum = fmaf(v0.x, v0.x, ssum); ssum = fmaf(v0.y, v0.y, ssum);
    ssum = fmaf(v0.z, v0.z, ssum); ssum = fmaf(v0.w, v0.w, ssum);
    ssum = fmaf(v1.x, v1.x, ssum); ssum = fmaf(v1.y, v1.y, ssum);
    ssum = fmaf(v1.z, v1.z, ssum); ssum = fmaf(v1.w, v1.w, ssum);
  }
  unsigned ua = __builtin_bit_cast(unsigned, ssum), ub = ua;
  plswap(ua, ub);
  const float b2v =
      __builtin_bit_cast(float, ua) + __builtin_bit_cast(float, ub);

#pragma unroll
  for (int j = 0; j < 8; ++j) AN[j] = (_Float16)0.0f;
  if (hi == 0) {
    _Float16 bh = (_Float16)b2v;
    _Float16 bl = (_Float16)(b2v - (float)bh);
    AN[0] = (_Float16)(-1.0f);
    AN[1] = (_Float16)(-1.0f);
    AN[2] = -bh;
    AN[3] = -bl;
    AN[4] = -bh;
  }

  f32x16 pv;
#pragma unroll
  for (int r = 0; r < 16; ++r) pv[r] = 0.f;

  const uint4* xf4 = (const uint4*)xf;
  const uint4* yv4 = (const uint4*)yv;

  uint4 X0[5], X1[5];
  LOAD5(X0, n0)
  LOAD5(X1, n0 + 32)

  for (int s = 0; s < nslab; s += 2) {
    const int nb = n0 + s * 32;

    // V loads for both slabs issued early (consumed at the very end).
    short8 V00 = __builtin_bit_cast(short8, yv4[(size_t)(nb >> 4) * 64 + lane]);
    short8 V01 = __builtin_bit_cast(short8, yv4[(size_t)(nb >> 4) * 64 + 64 + lane]);
    short8 V10 = __builtin_bit_cast(short8, yv4[(size_t)(nb >> 4) * 64 + 128 + lane]);
    short8 V11 = __builtin_bit_cast(short8, yv4[(size_t)(nb >> 4) * 64 + 192 + lane]);

    // Interleaved dual MFMA chains (dep distance 2).
    f32x16 sA0, sA1;
#pragma unroll
    for (int r = 0; r < 16; ++r) { sA0[r] = 0.f; sA1[r] = 0.f; }
    __builtin_amdgcn_s_setprio(1);
    sA0 = mfma_h(__builtin_bit_cast(f16x8, X0[4]), AN, sA0);
    sA1 = mfma_h(__builtin_bit_cast(f16x8, X1[4]), AN, sA1);
#pragma unroll
    for (int ks = 0; ks < 4; ++ks) {
      sA0 = mfma_h(__builtin_bit_cast(f16x8, X0[ks]), AH[ks], sA0);
      sA1 = mfma_h(__builtin_bit_cast(f16x8, X1[ks]), AH[ks], sA1);
    }
    __builtin_amdgcn_s_setprio(0);

    // Reload X for slabs s+2, s+3 (registers just freed by the MFMAs above;
    // the two tails below cover the L2 latency).
    if (s + 2 < nslab) {
      LOAD5(X0, nb + 64)
      LOAD5(X1, nb + 96)
    }

    // Two independent tails; PV0 (matrix pipe) overlaps tail1 (VALU/trans).
    TAILPV(sA0, V00, V01)
    TAILPV(sA1, V10, V11)
  }

  // Epilogue: col 0 = sum(w), cols 1..8 = sum(w*y).
  float* pc = partial + (size_t)c * 9 * BATCH;
  if (lr < 9) {
#pragma unroll
    for (int r = 0; r < 16; ++r)
      pc[(size_t)lr * BATCH + (mrow0 + (r & 3) + 8 * (r >> 2) + 4 * hi)] = pv[r];
  }
}

// ---------------------------------------------------------------------------
// Pass 2: reduce chunks, divide.
// ---------------------------------------------------------------------------
__global__ __launch_bounds__(256) void grnn_pass2(const float* __restrict__ partial,
                                                  float* __restrict__ out, int nc) {
  int b = blockIdx.x * 256 + threadIdx.x;
  float s1 = 0.f;
  float s2[ODIM];
#pragma unroll
  for (int j = 0; j < ODIM; ++j) s2[j] = 0.f;
  for (int cc = 0; cc < nc; ++cc) {
    const float* p = partial + (size_t)cc * 9 * BATCH;
    s1 += p[b];
#pragma unroll
    for (int j = 0; j < ODIM; ++j) s2[j] += p[(size_t)(j + 1) * BATCH + b];
  }
  const float inv = 1.f / s1;
#pragma unroll
  for (int j = 0; j < ODIM; ++j) out[(size_t)b * ODIM + j] = s2[j] * inv;
}

// ---------------------------------------------------------------------------
extern "C" void kernel_launch(void* const* d_in, const int* in_sizes, int n_in,
                              void* d_out, int out_size, void* d_ws, size_t ws_size,
                              hipStream_t stream) {
  const float* batches = (const float*)d_in[0];  // [8192, 64]
  const float* xt      = (const float*)d_in[1];  // [16384, 64]
  const float* yt      = (const float*)d_in[2];  // [16384, 8]
  const float* beta    = (const float*)d_in[3];  // [1, 16384]
  float* out = (float*)d_out;                    // [8192, 8]

  const size_t xf_b = (size_t)(NTRAIN / 32) * 5 * 1024;    // 2.625 MB
  const size_t yv_b = (size_t)(NTRAIN / 16) * 64 * 16;     // 1 MB
  const size_t fixed = xf_b + yv_b;
  const size_t per_chunk = (size_t)9 * BATCH * 4;          // 288 KB

  int nc = 32;
  while (nc > 1 && fixed + (size_t)nc * per_chunk > ws_size) nc >>= 1;
  const int chunk_n = NTRAIN / nc;

  char* p = (char*)d_ws;
  u16* xf = (u16*)p;      p += xf_b;
  u16* yv = (u16*)p;      p += yv_b;
  float* partial = (float*)p;

  const int frag_threads = (NTRAIN / 32) * 5 * 64 + (NTRAIN / 16) * 64;
  k_frag<<<(frag_threads + 255) / 256, 256, 0, stream>>>(xt, yt, beta, xf, yv);
  grnn_pass1<<<(BATCH / 128) * nc, 256, 0, stream>>>(
      xf, yv, batches, partial, chunk_n, nc);
  grnn_pass2<<<BATCH / 256, 256, 0, stream>>>(partial, out, nc);
}